// Round 2
// baseline (1837.959 us; speedup 1.0000x reference)
//
#include <hip/hip_runtime.h>
#include <hip/hip_bf16.h>
#include <hip/hip_cooperative_groups.h>

namespace cg = cooperative_groups;

#define ROWS 18
#define HID 1024

__device__ __forceinline__ float dot4(float4 a, float4 b){
  return fmaf(a.x,b.x, fmaf(a.y,b.y, fmaf(a.z,b.z, a.w*b.w)));
}

// Skinny GEMM phase (device function). Block = 8 waves (512 thr).
// Wave w < NWACT owns NC contiguous columns starting at cb + w*NC.
// Activations staged in LDS in NP passes of PK K-elements; RMS folded in.
template<int K, int ASTR, int PK, int NP, int NWACT, int NC, int ACT, int CSTR,
         bool RMS, bool BIAS, bool ATOMIC>
__device__ __forceinline__ void phase_gemm(
    const float* __restrict__ Wt, const float* __restrict__ act,
    const float* __restrict__ bias, float* __restrict__ outp,
    float* __restrict__ sact, float* __restrict__ sred, float* __restrict__ sscale,
    int cb, int k0)
{
  const int tid  = threadIdx.x;
  const int w    = tid >> 6;
  const int lane = tid & 63;

  float acc[NC][ROWS];
  #pragma unroll
  for (int i = 0; i < NC; i++)
    #pragma unroll
    for (int r = 0; r < ROWS; r++) acc[i][r] = 0.f;

  float rs[3] = {0.f, 0.f, 0.f};

  for (int p = 0; p < NP; p++) {
    __syncthreads();
    // ---- stage activations into LDS (coalesced float4) ----
    constexpr int N4 = ROWS * PK / 4;
    for (int t4 = tid; t4 < N4; t4 += 512) {
      const int r  = t4 / (PK / 4);
      const int k4 = (t4 % (PK / 4)) * 4;
      const int kg = k0 + p * PK + k4;
      float4 v;
      if (ACT == 0) {
        v = *(const float4*)&act[(size_t)r * ASTR + kg];
      } else {
        float4 gv = *(const float4*)&act[(size_t)r * ASTR + kg];
        float4 uv = *(const float4*)&act[(size_t)r * ASTR + 4096 + kg];
        v.x = gv.x / (1.f + __expf(-gv.x)) * uv.x;
        v.y = gv.y / (1.f + __expf(-gv.y)) * uv.y;
        v.z = gv.z / (1.f + __expf(-gv.z)) * uv.z;
        v.w = gv.w / (1.f + __expf(-gv.w)) * uv.w;
      }
      *(float4*)&sact[r * PK + k4] = v;
    }
    __syncthreads();

    // ---- rms partial sumsq: wave w owns rows w, w+8, w+16 ----
    if (RMS) {
      #pragma unroll
      for (int t = 0; t < 3; t++) {
        const int r = w + 8 * t;
        if (r < ROWS) {
          float ss = 0.f;
          #pragma unroll
          for (int kk = 4 * lane; kk < PK; kk += 256) {
            float4 a = *(const float4*)&sact[r * PK + kk];
            ss += dot4(a, a);
          }
          rs[t] += ss;
        }
      }
    }

    // ---- main FMA: stream weights from HBM, MAC vs all 18 rows ----
    if (w < NWACT) {
      constexpr int NCH = PK / 256;
      #pragma unroll
      for (int ch = 0; ch < NCH; ch++) {
        const int kk = ch * 256 + 4 * lane;
        float4 wv[NC];
        #pragma unroll
        for (int i = 0; i < NC; i++)
          wv[i] = *(const float4*)&Wt[(size_t)(cb + w * NC + i) * K + k0 + p * PK + kk];
        #pragma unroll
        for (int r = 0; r < ROWS; r++) {
          float4 a = *(const float4*)&sact[r * PK + kk];
          #pragma unroll
          for (int i = 0; i < NC; i++)
            acc[i][r] = fmaf(wv[i].x, a.x, fmaf(wv[i].y, a.y,
                        fmaf(wv[i].z, a.z, fmaf(wv[i].w, a.w, acc[i][r]))));
        }
      }
    }
  }

  // ---- finalize rms scales ----
  if (RMS) {
    #pragma unroll
    for (int t = 0; t < 3; t++) {
      const int r = w + 8 * t;
      if (r < ROWS) {
        float ss = rs[t];
        #pragma unroll
        for (int m = 32; m >= 1; m >>= 1) ss += __shfl_xor(ss, m);
        if (lane == 0) sscale[r] = rsqrtf(ss);
      }
    }
  }

  // ---- wave butterfly reduce -> LDS ----
  if (w < NWACT) {
    #pragma unroll
    for (int i = 0; i < NC; i++)
      #pragma unroll
      for (int r = 0; r < ROWS; r++) {
        float v = acc[i][r];
        #pragma unroll
        for (int m = 32; m >= 1; m >>= 1) v += __shfl_xor(v, m);
        if (lane == 0) sred[(w * NC + i) * ROWS + r] = v;
      }
  }
  __syncthreads();

  // ---- epilogue ----
  constexpr int TOT = NWACT * NC * ROWS;
  for (int t = tid; t < TOT; t += 512) {
    const int r    = t % ROWS;
    const int rest = t / ROWS;
    const int c    = cb + rest;
    float v = sred[rest * ROWS + r];
    if (RMS)  v *= sscale[r];
    if (BIAS) v += bias[c];
    if (ATOMIC) atomicAdd(&outp[(size_t)r * CSTR + c], v);
    else        outp[(size_t)r * CSTR + c] = v;
  }
}

__global__ __launch_bounds__(512, 2)
void voxcpm_fused(const int* __restrict__ step, const float* __restrict__ random_,
                  const float* __restrict__ dit_h, const float* __restrict__ feat,
                  const float* __restrict__ cfg, const float* __restrict__ cfgm,
                  const float* __restrict__ t_emb, const float* __restrict__ dt,
                  const float* __restrict__ in_w, const float* __restrict__ in_b,
                  const float* __restrict__ qkv_w, const float* __restrict__ qkv_b,
                  const float* __restrict__ o_w, const float* __restrict__ gu_w,
                  const float* __restrict__ dn_w, const float* __restrict__ op_w,
                  const float* __restrict__ op_b,
                  float* __restrict__ hs, float* __restrict__ qkvb,
                  float* __restrict__ attnb, float* __restrict__ gub,
                  float* __restrict__ outtmp, float* __restrict__ dout)
{
  cg::grid_group grid = cg::this_grid();
  __shared__ float sact[ROWS * 512];
  __shared__ float sred[8 * 4 * ROWS];
  __shared__ float sscale[ROWS];
  __shared__ float smisc[144];

  const int b   = blockIdx.x;
  const int tid = threadIdx.x;

  // ================= prep: build hs[18][1024] =================
  if (b < 2) {
    const int c  = b * 512 + tid;
    const int st = step[0];
    const float tv = t_emb[(size_t)st * HID + c];
    hs[0 * HID + c] = dit_h[c] + tv;
    hs[9 * HID + c] = tv;
    #pragma unroll
    for (int p = 0; p < 4; p++) {
      hs[(1 + p) * HID + c]  = feat[(size_t)(0 * 4 + p) * HID + c];
      hs[(10 + p) * HID + c] = feat[(size_t)(1 * 4 + p) * HID + c];
    }
    #pragma unroll
    for (int p = 0; p < 4; p++) {
      float a = in_b[c];
      #pragma unroll
      for (int q4 = 0; q4 < 16; q4++) {
        float4 wv = *(const float4*)&in_w[(size_t)c * 64 + q4 * 4];
        float4 rv = *(const float4*)&random_[p * 64 + q4 * 4];
        a += dot4(wv, rv);
      }
      hs[(5 + p) * HID + c]  = a;
      hs[(14 + p) * HID + c] = a;
    }
  }
  grid.sync();

  // ================= 8 transformer layers =================
  for (int i = 0; i < 8; i++) {
    const float* qw = qkv_w + (size_t)i * 3072 * 1024;
    const float* qb = qkv_b + (size_t)i * 3072;
    const float* ow = o_w   + (size_t)i * 1024 * 1024;
    const float* gw = gu_w  + (size_t)i * 8192 * 1024;
    const float* dw = dn_w  + (size_t)i * 1024 * 4096;

    // QKV: C=3072, 12 cols/block (6 waves x 2), rms+bias
    phase_gemm<1024, 1024, 512, 2, 6, 2, 0, 3072, true, true, false>
        (qw, hs, qb, qkvb, sact, sred, sscale, b * 12, 0);
    grid.sync();

    // attn: 32 (batch,head) problems on blocks 0..31, wave 0
    if (b < 32 && tid < 64) {
      const int bb = b >> 4, h = b & 15, d = tid;
      const float* base = qkvb + (size_t)bb * 9 * 3072;
      float q[9], k[9], v[9];
      #pragma unroll
      for (int ii = 0; ii < 9; ii++) {
        q[ii] = base[ii * 3072 + h * 64 + d];
        k[ii] = base[ii * 3072 + (16 + h) * 64 + d];
        v[ii] = base[ii * 3072 + (32 + h) * 64 + d];
      }
      const int j = d & 31;
      const float inv = powf(10000.f, -(float)j * (1.f / 32.f));
      #pragma unroll
      for (int ii = 0; ii < 9; ii++) {
        const float ang = (float)ii * inv;
        float sn, cs;
        __sincosf(ang, &sn, &cs);
        const float sgn = (d < 32) ? -sn : sn;
        const float rq = __shfl_xor(q[ii], 32);
        const float rk = __shfl_xor(k[ii], 32);
        q[ii] = q[ii] * cs + rq * sgn;
        k[ii] = k[ii] * cs + rk * sgn;
      }
      float* obase = attnb + (size_t)bb * 9 * HID + h * 64 + d;
      for (int ii = 0; ii < 9; ii++) {
        float sc[9];
        #pragma unroll
        for (int jj = 0; jj < 9; jj++) {
          float p = q[ii] * k[jj];
          #pragma unroll
          for (int m = 32; m >= 1; m >>= 1) p += __shfl_xor(p, m);
          sc[jj] = p;
        }
        float mx = sc[0];
        #pragma unroll
        for (int jj = 1; jj < 9; jj++) mx = fmaxf(mx, sc[jj]);
        float den = 0.f;
        #pragma unroll
        for (int jj = 0; jj < 9; jj++) { sc[jj] = __expf(sc[jj] - mx); den += sc[jj]; }
        float o = 0.f;
        #pragma unroll
        for (int jj = 0; jj < 9; jj++) o += sc[jj] * v[jj];
        obase[ii * HID] = o / den;
      }
    }
    grid.sync();

    // O: C=1024, K-split 4 (KB=256), 16 cols x 64 colgroups, atomic += hs
    phase_gemm<1024, 1024, 256, 1, 8, 2, 0, 1024, false, false, true>
        (ow, attnb, nullptr, hs, sact, sred, sscale, (b & 63) * 16, (b >> 6) * 256);
    grid.sync();

    // gate_up: C=8192, 32 cols/block (8 waves x 4), rms
    phase_gemm<1024, 1024, 512, 2, 8, 4, 0, 8192, true, false, false>
        (gw, hs, nullptr, gub, sact, sred, sscale, b * 32, 0);
    grid.sync();

    // down: C=1024, K=4096 split 4 (KB=1024), silu staging, atomic += hs
    phase_gemm<4096, 8192, 512, 2, 8, 2, 1, 1024, false, false, true>
        (dw, gub, nullptr, hs, sact, sred, sscale, (b & 63) * 16, (b >> 6) * 1024);
    grid.sync();
  }

  // ================= out_proj: blocks 0..63, one column each =================
  if (b < 64) {
    const int c = b;
    const int w = tid >> 6, lane = tid & 63;
    float* la = smisc;       // [8][8]
    float* ls = smisc + 64;  // [8][8]
    const float2 wv = ((const float2*)&op_w[(size_t)c * HID])[tid];
    #pragma unroll
    for (int r8 = 0; r8 < 8; r8++) {
      const int row = (r8 >> 2) * 9 + 5 + (r8 & 3);
      const float2 hv = ((const float2*)&hs[(size_t)row * HID])[tid];
      float a = fmaf(wv.x, hv.x, wv.y * hv.y);
      float s = fmaf(hv.x, hv.x, hv.y * hv.y);
      #pragma unroll
      for (int m = 32; m >= 1; m >>= 1) { a += __shfl_xor(a, m); s += __shfl_xor(s, m); }
      if (lane == 0) { la[r8 * 8 + w] = a; ls[r8 * 8 + w] = s; }
    }
    __syncthreads();
    if (tid < 8) {
      float a = 0.f, s = 0.f;
      #pragma unroll
      for (int jj = 0; jj < 8; jj++) { a += la[tid * 8 + jj]; s += ls[tid * 8 + jj]; }
      outtmp[tid * 64 + c] = a * rsqrtf(s) + op_b[c];
    }
  }
  grid.sync();

  // ================= CFG combine =================
  if (b == 0) {
    const int w = tid >> 6, lane = tid & 63;
    float pos = 0.f, neg = 0.f, d = 0.f, s = 0.f;
    if (tid < 256) {
      pos = outtmp[tid]; neg = outtmp[256 + tid];
      d = pos * neg; s = neg * neg;
    }
    #pragma unroll
    for (int m = 32; m >= 1; m >>= 1) { d += __shfl_xor(d, m); s += __shfl_xor(s, m); }
    float* ld  = smisc;
    float* lsq = smisc + 8;
    if (lane == 0) { ld[w] = d; lsq[w] = s; }
    __syncthreads();
    if (tid < 256) {
      float dot = 0.f, sq = 0.f;
      #pragma unroll
      for (int jj = 0; jj < 8; jj++) { dot += ld[jj]; sq += lsq[jj]; }
      const float guided = cfg[0] * pos + cfgm[0] * (dot / sq) * neg;
      dout[tid] = random_[tid] + guided * dt[step[0]];
    }
  }
}

extern "C" void kernel_launch(void* const* d_in, const int* in_sizes, int n_in,
                              void* d_out, int out_size, void* d_ws, size_t ws_size,
                              hipStream_t stream)
{
  const int*   step    = (const int*)  d_in[0];
  const float* random_ = (const float*)d_in[1];
  const float* dit_h   = (const float*)d_in[2];
  const float* feat    = (const float*)d_in[3];
  const float* cfg     = (const float*)d_in[4];
  const float* cfgm    = (const float*)d_in[5];
  const float* t_emb   = (const float*)d_in[6];
  const float* dt      = (const float*)d_in[7];
  const float* in_w    = (const float*)d_in[8];
  const float* in_b    = (const float*)d_in[9];
  const float* qkv_w   = (const float*)d_in[10];
  const float* qkv_b   = (const float*)d_in[11];
  const float* o_w     = (const float*)d_in[12];
  const float* gu_w    = (const float*)d_in[13];
  const float* dn_w    = (const float*)d_in[14];
  const float* op_w    = (const float*)d_in[15];
  const float* op_b    = (const float*)d_in[16];

  float* hs     = (float*)d_ws;          // 18*1024
  float* qkvb   = hs    + ROWS * HID;    // 18*3072
  float* attnb  = qkvb  + ROWS * 3072;   // 18*1024
  float* gub    = attnb + ROWS * HID;    // 18*8192
  float* outtmp = gub   + ROWS * 8192;   // 512
  float* dout   = (float*)d_out;

  void* args[] = {
    (void*)&step, (void*)&random_, (void*)&dit_h, (void*)&feat, (void*)&cfg,
    (void*)&cfgm, (void*)&t_emb, (void*)&dt, (void*)&in_w, (void*)&in_b,
    (void*)&qkv_w, (void*)&qkv_b, (void*)&o_w, (void*)&gu_w, (void*)&dn_w,
    (void*)&op_w, (void*)&op_b,
    (void*)&hs, (void*)&qkvb, (void*)&attnb, (void*)&gub, (void*)&outtmp,
    (void*)&dout
  };
  hipLaunchCooperativeKernel((void*)voxcpm_fused, dim3(256), dim3(512),
                             args, 0, stream);
}

// Round 3
// 948.185 us; speedup vs baseline: 1.9384x; 1.9384x over previous
//
#include <hip/hip_runtime.h>
#include <hip/hip_bf16.h>

#define ROWS 18
#define HID 1024

__device__ __forceinline__ float dot4(float4 a, float4 b){
  return fmaf(a.x,b.x, fmaf(a.y,b.y, fmaf(a.z,b.z, a.w*b.w)));
}
__device__ __forceinline__ void fma4(float& acc, float4 w, float4 a){
  acc = fmaf(w.x,a.x, fmaf(w.y,a.y, fmaf(w.z,a.z, fmaf(w.w,a.w, acc))));
}

// Skinny GEMM: out[18][C] = [rms(act)] [18][K-slice] @ W[C][K]^T (+bias) (+atomic)
// Block = 4 waves x NC=4 cols = 16 cols. grid.x = C/16, grid.y = K/KB splits.
// Weight loads issued BEFORE staging barrier -> latency hidden. NP = KB/PK passes (<=2).
template<int K, int ASTR, int KB, int PK, int CSTR, bool RMS, bool BIAS, bool ATOMIC, bool SPLITBUF>
__global__ __launch_bounds__(256)
void gemm_k(const float* __restrict__ Wt, const float* __restrict__ act,
            const float* __restrict__ bias, float* __restrict__ outp)
{
  constexpr int NP  = KB / PK;
  constexpr int NCH = PK / 256;
  static_assert(NP <= 2, "");

  __shared__ float sact[ROWS * PK];
  __shared__ float sred[16 * ROWS];
  __shared__ float sscale[ROWS];

  const int tid  = threadIdx.x;
  const int w    = tid >> 6;
  const int lane = tid & 63;
  const int cb   = blockIdx.x * 16;
  const int k0   = blockIdx.y * KB;

  float4 wva[NCH * 4], wvb[NCH * 4];
  float  acc[4][ROWS];
  #pragma unroll
  for (int i = 0; i < 4; i++)
    #pragma unroll
    for (int r = 0; r < ROWS; r++) acc[i][r] = 0.f;

  auto wissue = [&](float4* wv, int p) {
    #pragma unroll
    for (int ch = 0; ch < NCH; ch++)
      #pragma unroll
      for (int i = 0; i < 4; i++)
        wv[ch * 4 + i] = *(const float4*)&Wt[(size_t)(cb + w * 4 + i) * K +
                                             k0 + p * PK + ch * 256 + 4 * lane];
  };
  auto stage = [&](int p) {
    constexpr int N4 = ROWS * PK / 4;
    for (int t4 = tid; t4 < N4; t4 += 256) {
      const int r  = t4 / (PK / 4);
      const int k4 = (t4 % (PK / 4)) * 4;
      *(float4*)&sact[r * PK + k4] =
          *(const float4*)&act[(size_t)r * ASTR + k0 + p * PK + k4];
    }
  };
  auto dofma = [&](const float4* wv) {
    #pragma unroll
    for (int ch = 0; ch < NCH; ch++)
      #pragma unroll
      for (int r = 0; r < ROWS; r++) {
        float4 a = *(const float4*)&sact[r * PK + ch * 256 + 4 * lane];
        #pragma unroll
        for (int i = 0; i < 4; i++) fma4(acc[i][r], wv[ch * 4 + i], a);
      }
  };

  wissue(wva, 0);

  // RMS: full-row sumsq straight from global (independent of K-split)
  float rs[5] = {0.f,0.f,0.f,0.f,0.f};
  if (RMS) {
    #pragma unroll
    for (int t = 0; t < 5; t++) {
      const int r = w + 4 * t;
      if (r < ROWS) {
        #pragma unroll
        for (int kk = 4 * lane; kk < K; kk += 256) {
          float4 a = *(const float4*)&act[(size_t)r * ASTR + kk];
          rs[t] += dot4(a, a);
        }
      }
    }
  }

  stage(0);
  __syncthreads();
  if (NP > 1) wissue(wvb, 1);
  dofma(wva);
  if (NP > 1) {
    __syncthreads();
    stage(1);
    __syncthreads();
    dofma(wvb);
  }

  if (RMS) {
    #pragma unroll
    for (int t = 0; t < 5; t++) {
      const int r = w + 4 * t;
      if (r < ROWS) {
        float ss = rs[t];
        #pragma unroll
        for (int m = 32; m >= 1; m >>= 1) ss += __shfl_xor(ss, m);
        if (lane == 0) sscale[r] = rsqrtf(ss);
      }
    }
  }

  #pragma unroll
  for (int i = 0; i < 4; i++)
    #pragma unroll
    for (int r = 0; r < ROWS; r++) {
      float v = acc[i][r];
      #pragma unroll
      for (int m = 32; m >= 1; m >>= 1) v += __shfl_xor(v, m);
      if (lane == 0) sred[(w * 4 + i) * ROWS + r] = v;
    }
  __syncthreads();

  float* op = outp + (SPLITBUF ? (size_t)blockIdx.y * ROWS * CSTR : 0);
  for (int t = tid; t < 16 * ROWS; t += 256) {
    const int r    = t % ROWS;
    const int rest = t / ROWS;
    const int c    = cb + rest;
    float v = sred[rest * ROWS + r];
    if (RMS)  v *= sscale[r];
    if (BIAS) { if (blockIdx.y == 0) v += bias[c]; }
    if (ATOMIC) atomicAdd(&op[(size_t)r * CSTR + c], v);
    else        op[(size_t)r * CSTR + c] = v;
  }
}

// gate_up + silu fused: block = 16 output cols; waves 0-3 gate, 4-7 up.
__global__ __launch_bounds__(512)
void gu_kernel(const float* __restrict__ Wt, const float* __restrict__ act,
               float* __restrict__ gub)
{
  __shared__ float sact[ROWS * 512];
  __shared__ float sred[32 * ROWS];
  __shared__ float sscale[ROWS];

  const int tid  = threadIdx.x;
  const int w    = tid >> 6;
  const int lane = tid & 63;
  const int cb   = blockIdx.x * 16;
  const int wrow0 = (w >= 4 ? 4096 : 0) + cb + (w & 3) * 4;

  float4 wva[8], wvb[8];
  float  acc[4][ROWS];
  #pragma unroll
  for (int i = 0; i < 4; i++)
    #pragma unroll
    for (int r = 0; r < ROWS; r++) acc[i][r] = 0.f;

  auto wissue = [&](float4* wv, int p) {
    #pragma unroll
    for (int ch = 0; ch < 2; ch++)
      #pragma unroll
      for (int i = 0; i < 4; i++)
        wv[ch * 4 + i] = *(const float4*)&Wt[(size_t)(wrow0 + i) * 1024 +
                                             p * 512 + ch * 256 + 4 * lane];
  };
  auto stage = [&](int p) {
    for (int t4 = tid; t4 < ROWS * 128; t4 += 512) {
      const int r  = t4 / 128;
      const int k4 = (t4 % 128) * 4;
      *(float4*)&sact[r * 512 + k4] =
          *(const float4*)&act[(size_t)r * 1024 + p * 512 + k4];
    }
  };
  auto dofma = [&](const float4* wv) {
    #pragma unroll
    for (int ch = 0; ch < 2; ch++)
      #pragma unroll
      for (int r = 0; r < ROWS; r++) {
        float4 a = *(const float4*)&sact[r * 512 + ch * 256 + 4 * lane];
        #pragma unroll
        for (int i = 0; i < 4; i++) fma4(acc[i][r], wv[ch * 4 + i], a);
      }
  };

  wissue(wva, 0);

  float rs[3] = {0.f, 0.f, 0.f};
  #pragma unroll
  for (int t = 0; t < 3; t++) {
    const int r = w + 8 * t;
    if (r < ROWS) {
      #pragma unroll
      for (int kk = 4 * lane; kk < 1024; kk += 256) {
        float4 a = *(const float4*)&act[(size_t)r * 1024 + kk];
        rs[t] += dot4(a, a);
      }
    }
  }

  stage(0);
  __syncthreads();
  wissue(wvb, 1);
  dofma(wva);
  __syncthreads();
  stage(1);
  __syncthreads();
  dofma(wvb);

  #pragma unroll
  for (int t = 0; t < 3; t++) {
    const int r = w + 8 * t;
    if (r < ROWS) {
      float ss = rs[t];
      #pragma unroll
      for (int m = 32; m >= 1; m >>= 1) ss += __shfl_xor(ss, m);
      if (lane == 0) sscale[r] = rsqrtf(ss);
    }
  }

  #pragma unroll
  for (int i = 0; i < 4; i++)
    #pragma unroll
    for (int r = 0; r < ROWS; r++) {
      float v = acc[i][r];
      #pragma unroll
      for (int m = 32; m >= 1; m >>= 1) v += __shfl_xor(v, m);
      if (lane == 0) sred[(w * 4 + i) * ROWS + r] = v;
    }
  __syncthreads();

  for (int t = tid; t < 16 * ROWS; t += 512) {
    const int r = t >> 4;
    const int j = t & 15;
    const float s = sscale[r];
    const float g = sred[j * ROWS + r] * s;
    const float u = sred[(16 + j) * ROWS + r] * s;
    gub[(size_t)r * 4096 + cb + j] = (g / (1.f + __expf(-g))) * u;
  }
}

// Build hs[18][1024]
__global__ __launch_bounds__(256)
void prep_kernel(const int* __restrict__ step, const float* __restrict__ random_,
                 const float* __restrict__ dit_hidden, const float* __restrict__ feat_cond,
                 const float* __restrict__ t_emb, const float* __restrict__ in_w,
                 const float* __restrict__ in_b, float* __restrict__ hs)
{
  const int c = blockIdx.x * 256 + threadIdx.x;
  const int st = step[0];
  const float tv = t_emb[(size_t)st * HID + c];
  hs[0 * HID + c] = dit_hidden[c] + tv;
  hs[9 * HID + c] = tv;
  #pragma unroll
  for (int p = 0; p < 4; p++) {
    hs[(1 + p) * HID + c]  = feat_cond[(size_t)(0 * 4 + p) * HID + c];
    hs[(10 + p) * HID + c] = feat_cond[(size_t)(1 * 4 + p) * HID + c];
  }
  #pragma unroll
  for (int p = 0; p < 4; p++) {
    float a = in_b[c];
    #pragma unroll
    for (int q4 = 0; q4 < 16; q4++) {
      float4 wv = *(const float4*)&in_w[(size_t)c * 64 + q4 * 4];
      float4 rv = *(const float4*)&random_[p * 64 + q4 * 4];
      a += dot4(wv, rv);
    }
    hs[(5 + p) * HID + c]  = a;
    hs[(14 + p) * HID + c] = a;
  }
}

// One wave per (batch, head). Sums the two QKV K-split partials on load.
__global__ __launch_bounds__(64)
void attn_kernel(const float* __restrict__ qkvp, float* __restrict__ attn_out)
{
  const int bh = blockIdx.x;
  const int b = bh >> 4, h = bh & 15;
  const int d = threadIdx.x;
  const float* p0 = qkvp + (size_t)b * 9 * 3072;
  const float* p1 = p0 + (size_t)ROWS * 3072;
  float q[9], k[9], v[9];
  #pragma unroll
  for (int i = 0; i < 9; i++) {
    q[i] = p0[i * 3072 + h * 64 + d]        + p1[i * 3072 + h * 64 + d];
    k[i] = p0[i * 3072 + (16 + h) * 64 + d] + p1[i * 3072 + (16 + h) * 64 + d];
    v[i] = p0[i * 3072 + (32 + h) * 64 + d] + p1[i * 3072 + (32 + h) * 64 + d];
  }
  const int j = d & 31;
  const float inv = powf(10000.f, -(float)j * (1.f / 32.f));
  #pragma unroll
  for (int i = 0; i < 9; i++) {
    const float ang = (float)i * inv;
    float sn, cs;
    __sincosf(ang, &sn, &cs);
    const float sgn = (d < 32) ? -sn : sn;
    const float rq = __shfl_xor(q[i], 32);
    const float rk = __shfl_xor(k[i], 32);
    q[i] = q[i] * cs + rq * sgn;
    k[i] = k[i] * cs + rk * sgn;
  }
  float* obase = attn_out + (size_t)b * 9 * HID + h * 64 + d;
  for (int i = 0; i < 9; i++) {
    float sc[9];
    #pragma unroll
    for (int jj = 0; jj < 9; jj++) {
      float p = q[i] * k[jj];
      #pragma unroll
      for (int m = 32; m >= 1; m >>= 1) p += __shfl_xor(p, m);
      sc[jj] = p;
    }
    float mx = sc[0];
    #pragma unroll
    for (int jj = 1; jj < 9; jj++) mx = fmaxf(mx, sc[jj]);
    float den = 0.f;
    #pragma unroll
    for (int jj = 0; jj < 9; jj++) { sc[jj] = __expf(sc[jj] - mx); den += sc[jj]; }
    float o = 0.f;
    #pragma unroll
    for (int jj = 0; jj < 9; jj++) o += sc[jj] * v[jj];
    obase[i * HID] = o / den;
  }
}

// out_proj + CFG combine, single block of 512.
__global__ __launch_bounds__(512)
void outcomb_kernel(const float* __restrict__ hs, const float* __restrict__ opw,
                    const float* __restrict__ opb, const float* __restrict__ random_,
                    const float* __restrict__ cfg, const float* __restrict__ cfgm,
                    const float* __restrict__ dt, const int* __restrict__ step,
                    float* __restrict__ dout)
{
  __shared__ float sh[8 * 1024];
  __shared__ float sscale[8];
  __shared__ float sout[512];
  __shared__ float sdot[4], ssq[4];

  const int tid = threadIdx.x;
  const int w = tid >> 6, lane = tid & 63;

  for (int t4 = tid; t4 < 2048; t4 += 512) {
    const int r8 = t4 / 256;
    const int k4 = (t4 % 256) * 4;
    const int row = (r8 >> 2) * 9 + 5 + (r8 & 3);
    *(float4*)&sh[r8 * 1024 + k4] = *(const float4*)&hs[(size_t)row * 1024 + k4];
  }
  __syncthreads();

  {
    float ss = 0.f;
    #pragma unroll
    for (int qq = 0; qq < 4; qq++) {
      float4 a = *(const float4*)&sh[w * 1024 + 4 * lane + 256 * qq];
      ss += dot4(a, a);
    }
    #pragma unroll
    for (int m = 32; m >= 1; m >>= 1) ss += __shfl_xor(ss, m);
    if (lane == 0) sscale[w] = rsqrtf(ss);
  }
  __syncthreads();

  {
    const int r8 = tid & 7;
    const int c  = tid >> 3;
    float a0 = 0.f, a1 = 0.f;
    #pragma unroll 4
    for (int k4 = 0; k4 < 128; k4++) {
      a0 += dot4(*(const float4*)&sh[r8 * 1024 + 8 * k4],
                 *(const float4*)&opw[(size_t)c * 1024 + 8 * k4]);
      a1 += dot4(*(const float4*)&sh[r8 * 1024 + 8 * k4 + 4],
                 *(const float4*)&opw[(size_t)c * 1024 + 8 * k4 + 4]);
    }
    sout[r8 * 64 + c] = (a0 + a1) * sscale[r8] + opb[c];
  }
  __syncthreads();

  float pos = 0.f, neg = 0.f, dd = 0.f, sq = 0.f;
  if (tid < 256) {
    pos = sout[tid]; neg = sout[256 + tid];
    dd = pos * neg; sq = neg * neg;
  }
  #pragma unroll
  for (int m = 32; m >= 1; m >>= 1) { dd += __shfl_xor(dd, m); sq += __shfl_xor(sq, m); }
  if (w < 4 && lane == 0) { sdot[w] = dd; ssq[w] = sq; }
  __syncthreads();
  if (tid < 256) {
    const float dot = sdot[0] + sdot[1] + sdot[2] + sdot[3];
    const float sqs = ssq[0] + ssq[1] + ssq[2] + ssq[3];
    const float guided = cfg[0] * pos + cfgm[0] * (dot / sqs) * neg;
    dout[tid] = random_[tid] + guided * dt[step[0]];
  }
}

extern "C" void kernel_launch(void* const* d_in, const int* in_sizes, int n_in,
                              void* d_out, int out_size, void* d_ws, size_t ws_size,
                              hipStream_t stream)
{
  const int*   step    = (const int*)  d_in[0];
  const float* random_ = (const float*)d_in[1];
  const float* dit_h   = (const float*)d_in[2];
  const float* feat    = (const float*)d_in[3];
  const float* cfg     = (const float*)d_in[4];
  const float* cfgm    = (const float*)d_in[5];
  const float* t_emb   = (const float*)d_in[6];
  const float* dt      = (const float*)d_in[7];
  const float* in_w    = (const float*)d_in[8];
  const float* in_b    = (const float*)d_in[9];
  const float* qkv_w   = (const float*)d_in[10];
  const float* qkv_b   = (const float*)d_in[11];
  const float* o_w     = (const float*)d_in[12];
  const float* gu_w    = (const float*)d_in[13];
  const float* dn_w    = (const float*)d_in[14];
  const float* op_w    = (const float*)d_in[15];
  const float* op_b    = (const float*)d_in[16];

  float* hs    = (float*)d_ws;            // 18*1024
  float* qkvp  = hs   + ROWS * HID;       // 2 * 18*3072 (K-split partials)
  float* attnb = qkvp + 2 * ROWS * 3072;  // 18*1024
  float* gub   = attnb + ROWS * HID;      // 18*4096 (silu applied)
  float* dout  = (float*)d_out;

  prep_kernel<<<4, 256, 0, stream>>>(step, random_, dit_h, feat, t_emb, in_w, in_b, hs);

  for (int i = 0; i < 8; i++) {
    const float* qw = qkv_w + (size_t)i * 3072 * 1024;
    const float* qb = qkv_b + (size_t)i * 3072;
    const float* ow = o_w   + (size_t)i * 1024 * 1024;
    const float* gw = gu_w  + (size_t)i * 8192 * 1024;
    const float* dw = dn_w  + (size_t)i * 1024 * 4096;

    // QKV: C=3072, K-split 2 into partial buffers, rms+bias. 384 blocks.
    gemm_k<1024, 1024, 512, 512, 3072, true, true, false, true>
        <<<dim3(192, 2), 256, 0, stream>>>(qw, hs, qb, qkvp);
    attn_kernel<<<32, 64, 0, stream>>>(qkvp, attnb);
    // O: K-split 4, atomic residual into hs. 256 blocks.
    gemm_k<1024, 1024, 256, 256, 1024, false, false, true, false>
        <<<dim3(64, 4), 256, 0, stream>>>(ow, attnb, nullptr, hs);
    // gate_up + silu: 256 blocks x 512 thr.
    gu_kernel<<<256, 512, 0, stream>>>(gw, hs, gub);
    // down: K=4096 split 4, atomic residual into hs. 256 blocks.
    gemm_k<4096, 4096, 1024, 512, 1024, false, false, true, false>
        <<<dim3(64, 4), 256, 0, stream>>>(dw, gub, nullptr, hs);
  }

  outcomb_kernel<<<1, 512, 0, stream>>>(hs, op_w, op_b, random_, cfg, cfgm, dt,
                                        step, dout);
}